// Round 1
// baseline (182.527 us; speedup 1.0000x reference)
//
#include <hip/hip_runtime.h>
#include <hip/hip_bf16.h>
#include <math.h>

// ---------- types ----------
typedef __attribute__((ext_vector_type(4))) float f32x4;
typedef __bf16 bf16x8 __attribute__((ext_vector_type(8)));

typedef void __attribute__((address_space(1))) * as1p;
typedef void __attribute__((address_space(3))) * as3p;

__device__ __forceinline__ unsigned short f2bf(float f) {
    union { float f; unsigned int u; } v; v.f = f;
    unsigned int u = v.u;
    u += 0x7fffu + ((u >> 16) & 1u);   // round-to-nearest-even
    return (unsigned short)(u >> 16);
}

// ---------- convert X, h_prev to bf16 ----------
__global__ void cvt_xh(const float* __restrict__ x, const float* __restrict__ h,
                       unsigned short* __restrict__ xb, unsigned short* __restrict__ hb,
                       int n4) {
    int i = blockIdx.x * blockDim.x + threadIdx.x;
    int stride = gridDim.x * blockDim.x;
    const float4* x4 = (const float4*)x;
    const float4* h4 = (const float4*)h;
    ushort4* xb4 = (ushort4*)xb;
    ushort4* hb4 = (ushort4*)hb;
    for (; i < n4; i += stride) {
        float4 v = x4[i];
        xb4[i] = make_ushort4(f2bf(v.x), f2bf(v.y), f2bf(v.z), f2bf(v.w));
        float4 w = h4[i];
        hb4[i] = make_ushort4(f2bf(w.x), f2bf(w.y), f2bf(w.z), f2bf(w.w));
    }
}

// ---------- transpose+convert one weight: src fp32 [1024][512] -> dst bf16 [512 rows][1024 cols] ----------
__global__ void tr_cvt(const float* __restrict__ src, unsigned short* __restrict__ dst) {
    __shared__ float t[32][33];
    int n0 = blockIdx.x * 32;   // src col tile -> dst row tile
    int k0 = blockIdx.y * 32;   // src row tile -> dst col tile
    int tx = threadIdx.x, ty = threadIdx.y;
#pragma unroll
    for (int i = 0; i < 4; ++i)
        t[ty + i * 8][tx] = src[(size_t)(k0 + ty + i * 8) * 512 + n0 + tx];
    __syncthreads();
#pragma unroll
    for (int i = 0; i < 4; ++i)
        dst[(size_t)(n0 + ty + i * 8) * 1024 + k0 + tx] = f2bf(t[tx][ty + i * 8]);
}

// ---------- stage a 128x64 bf16 tile into LDS via global_load_lds (width 16) ----------
// LDS layout: row-major [128][64] bf16 (128 B row stride), linear.
__device__ __forceinline__ void stage128x64(const unsigned short* g, int gstride,
                                            unsigned short* lds, int tid) {
    int w = tid >> 6;      // wave 0..3
    int l = tid & 63;      // lane
#pragma unroll
    for (int i = 0; i < 4; ++i) {
        int o = i * 4096 + w * 1024 + l * 16;   // byte offset in tile
        int row = o >> 7;                        // /128 B per row
        int ke = (o & 127) >> 1;                 // element within row
        const unsigned short* gp = g + (size_t)row * gstride + ke;
        unsigned short* lp = lds + ((i * 4096 + w * 1024) >> 1);  // WAVE-UNIFORM base; HW adds lane*16
        __builtin_amdgcn_global_load_lds((as1p)(void*)gp, (as3p)(void*)lp, 16, 0, 0);
    }
}

// ---------- GEMM1: [X|H] @ [Wz|Wr]^T-packed, epilogue -> zg (f32), rgh (bf16) ----------
// A: k<512 from Xb, else Hb (BK=64 divides 512).  B: WzrT [1024 N][1024 K] bf16.
__global__ __launch_bounds__(256) void gemm1(
    const unsigned short* __restrict__ Xb, const unsigned short* __restrict__ Hb,
    const unsigned short* __restrict__ Wt, const float* __restrict__ hp,
    const float* __restrict__ ub, const float* __restrict__ rb,
    float* __restrict__ zg, unsigned short* __restrict__ rgh) {
    __shared__ unsigned short ldsA[128 * 64];
    __shared__ unsigned short ldsB[128 * 64];
    int tid = threadIdx.x;
    int l = tid & 63, w = tid >> 6;
    int wr = w >> 1, wc = w & 1;
    int m0 = blockIdx.y * 128;
    int n0 = blockIdx.x * 128;
    f32x4 acc[4][4];
#pragma unroll
    for (int m = 0; m < 4; ++m)
#pragma unroll
        for (int n = 0; n < 4; ++n) acc[m][n] = (f32x4){0.f, 0.f, 0.f, 0.f};

    int fr = l & 15;
    int fk = (l >> 4) << 3;

    for (int k0 = 0; k0 < 1024; k0 += 64) {
        const unsigned short* gA = (k0 < 512) ? (Xb + (size_t)m0 * 512 + k0)
                                              : (Hb + (size_t)m0 * 512 + (k0 - 512));
        stage128x64(gA, 512, ldsA, tid);
        stage128x64(Wt + (size_t)n0 * 1024 + k0, 1024, ldsB, tid);
        __syncthreads();
#pragma unroll
        for (int kk = 0; kk < 64; kk += 32) {
            bf16x8 a[4], b[4];
#pragma unroll
            for (int m = 0; m < 4; ++m)
                a[m] = *(const bf16x8*)&ldsA[(wr * 64 + m * 16 + fr) * 64 + kk + fk];
#pragma unroll
            for (int n = 0; n < 4; ++n)
                b[n] = *(const bf16x8*)&ldsB[(wc * 64 + n * 16 + fr) * 64 + kk + fk];
#pragma unroll
            for (int m = 0; m < 4; ++m)
#pragma unroll
                for (int n = 0; n < 4; ++n)
                    acc[m][n] = __builtin_amdgcn_mfma_f32_16x16x32_bf16(a[m], b[n], acc[m][n], 0, 0, 0);
        }
        __syncthreads();
    }

    int colb = n0 + wc * 64;
    int rowb = m0 + wr * 64 + ((l >> 4) << 2);
#pragma unroll
    for (int n = 0; n < 4; ++n) {
        int col = colb + n * 16 + (l & 15);
        bool isZ = col < 512;
        int c = isZ ? col : col - 512;
        float bias = isZ ? ub[c] : rb[c];
#pragma unroll
        for (int m = 0; m < 4; ++m) {
            int row0 = rowb + m * 16;
#pragma unroll
            for (int r = 0; r < 4; ++r) {
                int row = row0 + r;
                float v = acc[m][n][r] + bias;
                float s = 1.f / (1.f + __expf(-v));
                if (isZ) zg[(size_t)row * 512 + c] = s;
                else     rgh[(size_t)row * 512 + c] = f2bf(s * hp[(size_t)row * 512 + c]);
            }
        }
    }
}

// ---------- GEMM2: [X|rgh] @ Wh, epilogue -> ht (f32 out) ----------
__global__ __launch_bounds__(256) void gemm2(
    const unsigned short* __restrict__ Xb, const unsigned short* __restrict__ rgh,
    const unsigned short* __restrict__ Wt, const float* __restrict__ hp,
    const float* __restrict__ zg, const float* __restrict__ hb,
    float* __restrict__ out) {
    __shared__ unsigned short ldsA[128 * 64];
    __shared__ unsigned short ldsB[128 * 64];
    int tid = threadIdx.x;
    int l = tid & 63, w = tid >> 6;
    int wr = w >> 1, wc = w & 1;
    int m0 = blockIdx.y * 128;
    int n0 = blockIdx.x * 128;
    f32x4 acc[4][4];
#pragma unroll
    for (int m = 0; m < 4; ++m)
#pragma unroll
        for (int n = 0; n < 4; ++n) acc[m][n] = (f32x4){0.f, 0.f, 0.f, 0.f};

    int fr = l & 15;
    int fk = (l >> 4) << 3;

    for (int k0 = 0; k0 < 1024; k0 += 64) {
        const unsigned short* gA = (k0 < 512) ? (Xb + (size_t)m0 * 512 + k0)
                                              : (rgh + (size_t)m0 * 512 + (k0 - 512));
        stage128x64(gA, 512, ldsA, tid);
        stage128x64(Wt + (size_t)n0 * 1024 + k0, 1024, ldsB, tid);
        __syncthreads();
#pragma unroll
        for (int kk = 0; kk < 64; kk += 32) {
            bf16x8 a[4], b[4];
#pragma unroll
            for (int m = 0; m < 4; ++m)
                a[m] = *(const bf16x8*)&ldsA[(wr * 64 + m * 16 + fr) * 64 + kk + fk];
#pragma unroll
            for (int n = 0; n < 4; ++n)
                b[n] = *(const bf16x8*)&ldsB[(wc * 64 + n * 16 + fr) * 64 + kk + fk];
#pragma unroll
            for (int m = 0; m < 4; ++m)
#pragma unroll
                for (int n = 0; n < 4; ++n)
                    acc[m][n] = __builtin_amdgcn_mfma_f32_16x16x32_bf16(a[m], b[n], acc[m][n], 0, 0, 0);
        }
        __syncthreads();
    }

    int colb = n0 + wc * 64;
    int rowb = m0 + wr * 64 + ((l >> 4) << 2);
#pragma unroll
    for (int n = 0; n < 4; ++n) {
        int col = colb + n * 16 + (l & 15);
        float bias = hb[col];
#pragma unroll
        for (int m = 0; m < 4; ++m) {
            int row0 = rowb + m * 16;
#pragma unroll
            for (int r = 0; r < 4; ++r) {
                int row = row0 + r;
                float v = acc[m][n][r] + bias;
                float t = tanhf(v);
                float h0 = hp[(size_t)row * 512 + col];
                float z = zg[(size_t)row * 512 + col];
                out[(size_t)row * 512 + col] = h0 + z * (t - h0);
            }
        }
    }
}

extern "C" void kernel_launch(void* const* d_in, const int* in_sizes, int n_in,
                              void* d_out, int out_size, void* d_ws, size_t ws_size,
                              hipStream_t stream) {
    const float* x  = (const float*)d_in[0];   // [16384,512]
    const float* h  = (const float*)d_in[1];   // [16384,512]
    const float* wz = (const float*)d_in[2];   // [1024,512]
    const float* wr = (const float*)d_in[3];   // [1024,512]
    const float* wh = (const float*)d_in[4];   // [1024,512]
    const float* ub = (const float*)d_in[5];
    const float* rb = (const float*)d_in[6];
    const float* hb = (const float*)d_in[7];
    float* out = (float*)d_out;

    const int B = 16384;
    char* ws = (char*)d_ws;
    size_t off = 0;
    unsigned short* Xb  = (unsigned short*)(ws + off); off += (size_t)B * 512 * 2;   // 16 MB
    unsigned short* Hb  = (unsigned short*)(ws + off); off += (size_t)B * 512 * 2;   // 16 MB
    unsigned short* Wzr = (unsigned short*)(ws + off); off += (size_t)1024 * 1024 * 2; // 2 MB
    unsigned short* Wht = (unsigned short*)(ws + off); off += (size_t)512 * 1024 * 2;  // 1 MB
    unsigned short* rgh = (unsigned short*)(ws + off); off += (size_t)B * 512 * 2;   // 16 MB
    float*          zg  = (float*)(ws + off);          off += (size_t)B * 512 * 4;   // 32 MB

    cvt_xh<<<2048, 256, 0, stream>>>(x, h, Xb, Hb, B * 512 / 4);

    dim3 tb(32, 8), tg(16, 32);
    tr_cvt<<<tg, tb, 0, stream>>>(wz, Wzr);
    tr_cvt<<<tg, tb, 0, stream>>>(wr, Wzr + (size_t)512 * 1024);
    tr_cvt<<<tg, tb, 0, stream>>>(wh, Wht);

    gemm1<<<dim3(8, 128), 256, 0, stream>>>(Xb, Hb, Wzr, h, ub, rb, zg, rgh);
    gemm2<<<dim3(4, 128), 256, 0, stream>>>(Xb, rgh, Wht, h, zg, hb, out);
}